// Round 1
// baseline (803.866 us; speedup 1.0000x reference)
//
#include <hip/hip_runtime.h>
#include <cstdint>

static constexpr int BLK = 256;

// ---------------------------------------------------------------- degrees ---
__global__ __launch_bounds__(BLK) void k_init_deg(float* __restrict__ deg_f,
                                                  float* __restrict__ deg_b, int n) {
    int i = blockIdx.x * BLK + threadIdx.x;
    if (i < n) { deg_f[i] = 1.0f; deg_b[i] = 1.0f; }   // self-loop
}

__global__ __launch_bounds__(BLK) void k_count_deg(const int* __restrict__ src,
                                                   const int* __restrict__ dst,
                                                   float* __restrict__ deg_f,
                                                   float* __restrict__ deg_b, int ne) {
    int e = blockIdx.x * BLK + threadIdx.x;
    if (e < ne) {
        atomicAdd(deg_f + dst[e], 1.0f);   // fwd conv: in-degree
        atomicAdd(deg_b + src[e], 1.0f);   // bwd conv: in-degree of reversed graph
    }
}

__global__ __launch_bounds__(BLK) void k_rsqrt(float* __restrict__ deg_f,
                                               float* __restrict__ deg_b, int n) {
    int i = blockIdx.x * BLK + threadIdx.x;
    if (i < n) {
        deg_f[i] = rsqrtf(deg_f[i]);       // in-place: deg -> dinv
        deg_b[i] = rsqrtf(deg_b[i]);
    }
}

// ------------------------------------------------------------------- GEMM ---
// hs_f[r][c] = (sum_k x[r][k] * Wf[k][c]) * dinv_f[r]   (and same for bwd)
// thread t: half = t>>7 selects fwd/bwd, c = t&127 is the output column.
// W column lives in 128 VGPRs; x[r][k] is wave-uniform -> scalar loads.
__global__ __launch_bounds__(BLK) void k_gemm(const float* __restrict__ x,
                                              const float* __restrict__ Wf,
                                              const float* __restrict__ Wb,
                                              const float* __restrict__ dinv_f,
                                              const float* __restrict__ dinv_b,
                                              float* __restrict__ hs_f,
                                              float* __restrict__ hs_b, int n) {
    const int t = threadIdx.x;
    const int c = t & 127;
    const int half = t >> 7;                       // wave-uniform (wave=64)
    const float* __restrict__ W    = half ? Wb : Wf;
    const float* __restrict__ dinv = half ? dinv_b : dinv_f;
    float* __restrict__ hs         = half ? hs_b : hs_f;

    float wcol[128];
#pragma unroll
    for (int k = 0; k < 128; ++k) wcol[k] = W[k * 128 + c];

    for (int r = blockIdx.x; r < n; r += gridDim.x) {
        const float* __restrict__ xr = x + (size_t)r * 128;
        float acc = 0.0f;
#pragma unroll
        for (int k = 0; k < 128; ++k) acc = fmaf(xr[k], wcol[k], acc);
        hs[(size_t)r * 128 + c] = acc * dinv[r];
    }
}

// --------------------------------------------- self-loop init of accumulator
// out[n][c] = hs_f[n][c]*dinv_f[n] + hs_b[n][c]*dinv_b[n]
__global__ __launch_bounds__(BLK) void k_self(const float* __restrict__ hs_f,
                                              const float* __restrict__ hs_b,
                                              const float* __restrict__ dinv_f,
                                              const float* __restrict__ dinv_b,
                                              float* __restrict__ out, int total) {
    int i = blockIdx.x * BLK + threadIdx.x;
    if (i < total) {
        int r = i >> 7;
        out[i] = hs_f[i] * dinv_f[r] + hs_b[i] * dinv_b[r];
    }
}

// ---------------------------------------------------------------- scatter ---
// per (edge, feature): fwd message hs_f[s]*dinv_f[d] -> out[d]
//                      bwd message hs_b[d]*dinv_b[s] -> out[s]
__global__ __launch_bounds__(BLK) void k_scatter(const int* __restrict__ src,
                                                 const int* __restrict__ dst,
                                                 const float* __restrict__ hs_f,
                                                 const float* __restrict__ hs_b,
                                                 const float* __restrict__ dinv_f,
                                                 const float* __restrict__ dinv_b,
                                                 float* __restrict__ out, int ne) {
    long tid = (long)blockIdx.x * BLK + threadIdx.x;
    int e = (int)(tid >> 7);
    if (e >= ne) return;
    int f = (int)(tid & 127);
    int s = src[e];
    int d = dst[e];
    float mf = hs_f[(size_t)s * 128 + f] * dinv_f[d];
    atomicAdd(out + (size_t)d * 128 + f, mf);
    float mb = hs_b[(size_t)d * 128 + f] * dinv_b[s];
    atomicAdd(out + (size_t)s * 128 + f, mb);
}

// ------------------------------------------------------------ bias + relu ---
__global__ __launch_bounds__(BLK) void k_finish(float* __restrict__ out,
                                                const float* __restrict__ bf,
                                                const float* __restrict__ bb, int total) {
    int i = blockIdx.x * BLK + threadIdx.x;
    if (i < total) {
        int c = i & 127;
        float v = out[i] + bf[c] + bb[c];
        out[i] = v > 0.0f ? v : 0.0f;
    }
}

// ---------------------------------------------------------------- launcher --
extern "C" void kernel_launch(void* const* d_in, const int* in_sizes, int n_in,
                              void* d_out, int out_size, void* d_ws, size_t ws_size,
                              hipStream_t stream) {
    const float* x  = (const float*)d_in[0];
    const int*   ei = (const int*)d_in[1];
    const float* Wf = (const float*)d_in[2];
    const float* bf = (const float*)d_in[3];
    const float* Wb = (const float*)d_in[4];
    const float* bb = (const float*)d_in[5];

    const int n  = in_sizes[0] / 128;   // 50000 nodes
    const int ne = in_sizes[1] / 2;     // 625000 edges
    const int* src = ei;                // edge_index[0]
    const int* dst = ei + ne;           // edge_index[1]
    float* out = (float*)d_out;

    // workspace layout (floats): dinv_f[n] | dinv_b[n] | hs_f[n*128] | hs_b[n*128]
    float* w     = (float*)d_ws;
    float* deg_f = w;
    float* deg_b = w + n;
    float* hs_f  = w + 2 * (size_t)n;
    float* hs_b  = hs_f + (size_t)n * 128;

    k_init_deg<<<(n + BLK - 1) / BLK, BLK, 0, stream>>>(deg_f, deg_b, n);
    k_count_deg<<<(ne + BLK - 1) / BLK, BLK, 0, stream>>>(src, dst, deg_f, deg_b, ne);
    k_rsqrt<<<(n + BLK - 1) / BLK, BLK, 0, stream>>>(deg_f, deg_b, n);
    k_gemm<<<2048, BLK, 0, stream>>>(x, Wf, Wb, deg_f, deg_b, hs_f, hs_b, n);

    const long total = (long)n * 128;
    k_self<<<(int)((total + BLK - 1) / BLK), BLK, 0, stream>>>(hs_f, hs_b, deg_f, deg_b,
                                                               out, (int)total);
    const long work = (long)ne * 128;
    k_scatter<<<(int)((work + BLK - 1) / BLK), BLK, 0, stream>>>(src, dst, hs_f, hs_b,
                                                                 deg_f, deg_b, out, ne);
    k_finish<<<(int)((total + BLK - 1) / BLK), BLK, 0, stream>>>(out, bf, bb, (int)total);
}

// Round 2
// 586.027 us; speedup vs baseline: 1.3717x; 1.3717x over previous
//
#include <hip/hip_runtime.h>
#include <cstdint>

static constexpr int BLK = 256;

// ------------------------------------------------------------ init ---------
// zero degree counters (int) for both directions
__global__ __launch_bounds__(BLK) void k_init(int* __restrict__ cnt_f,
                                              int* __restrict__ cnt_b, int n) {
    int i = blockIdx.x * BLK + threadIdx.x;
    if (i < n) { cnt_f[i] = 0; cnt_b[i] = 0; }
}

// ------------------------------------------------------------ degree count -
__global__ __launch_bounds__(BLK) void k_count(const int* __restrict__ src,
                                               const int* __restrict__ dst,
                                               int* __restrict__ cnt_f,
                                               int* __restrict__ cnt_b, int ne) {
    int e = blockIdx.x * BLK + threadIdx.x;
    if (e < ne) {
        atomicAdd(cnt_f + dst[e], 1);   // fwd conv groups by dst
        atomicAdd(cnt_b + src[e], 1);   // bwd conv groups by src
    }
}

// ------------------------------------------------------------ rsqrt(deg) ---
// deg = cnt + 1 (self-loop); dinv = rsqrt(deg)
__global__ __launch_bounds__(BLK) void k_rsqrt(const int* __restrict__ cnt_f,
                                               const int* __restrict__ cnt_b,
                                               float* __restrict__ dinv_f,
                                               float* __restrict__ dinv_b, int n) {
    int i = blockIdx.x * BLK + threadIdx.x;
    if (i < n) {
        dinv_f[i] = rsqrtf(1.0f + (float)cnt_f[i]);
        dinv_b[i] = rsqrtf(1.0f + (float)cnt_b[i]);
    }
}

// ------------------------------------------------------------ scan level 1 -
// each block scans a 1024-element chunk (4 per thread), writes block total
__global__ __launch_bounds__(BLK) void k_scan1(const int* __restrict__ in,
                                               int* __restrict__ out,
                                               int* __restrict__ bsum, int n) {
    __shared__ int lds[BLK];
    int base = blockIdx.x * 1024 + threadIdx.x * 4;
    int v0 = (base + 0 < n) ? in[base + 0] : 0;
    int v1 = (base + 1 < n) ? in[base + 1] : 0;
    int v2 = (base + 2 < n) ? in[base + 2] : 0;
    int v3 = (base + 3 < n) ? in[base + 3] : 0;
    int tsum = v0 + v1 + v2 + v3;
    lds[threadIdx.x] = tsum;
    __syncthreads();
    for (int off = 1; off < BLK; off <<= 1) {
        int t = (threadIdx.x >= off) ? lds[threadIdx.x - off] : 0;
        __syncthreads();
        lds[threadIdx.x] += t;
        __syncthreads();
    }
    int excl = lds[threadIdx.x] - tsum;
    if (base + 0 < n) out[base + 0] = excl;
    if (base + 1 < n) out[base + 1] = excl + v0;
    if (base + 2 < n) out[base + 2] = excl + v0 + v1;
    if (base + 3 < n) out[base + 3] = excl + v0 + v1 + v2;
    if (threadIdx.x == BLK - 1) bsum[blockIdx.x] = excl + tsum;
}

// ------------------------------------------------------------ scan level 2 -
// exclusive scan of block sums in place (nb <= 256), single block
__global__ __launch_bounds__(BLK) void k_scan2(int* __restrict__ bsum, int nb) {
    __shared__ int lds[BLK];
    int v = (threadIdx.x < nb) ? bsum[threadIdx.x] : 0;
    lds[threadIdx.x] = v;
    __syncthreads();
    for (int off = 1; off < BLK; off <<= 1) {
        int t = (threadIdx.x >= off) ? lds[threadIdx.x - off] : 0;
        __syncthreads();
        lds[threadIdx.x] += t;
        __syncthreads();
    }
    if (threadIdx.x < nb) bsum[threadIdx.x] = lds[threadIdx.x] - v;
}

// ------------------------------------------------------------ scan level 3 -
// add scanned block sums; duplicate into cursor array; cap entry off[n]=ne
__global__ __launch_bounds__(BLK) void k_scan3(int* __restrict__ off,
                                               int* __restrict__ cur,
                                               const int* __restrict__ bsum,
                                               int n, int ne) {
    int i = blockIdx.x * BLK + threadIdx.x;
    if (i < n) {
        int v = off[i] + bsum[i >> 10];
        off[i] = v;
        cur[i] = v;
    }
    if (i == 0) off[n] = ne;
}

// ------------------------------------------------------------ CSR fill -----
__global__ __launch_bounds__(BLK) void k_fill(const int* __restrict__ src,
                                              const int* __restrict__ dst,
                                              int* __restrict__ cur_f,
                                              int* __restrict__ cur_b,
                                              int* __restrict__ adj_f,
                                              int* __restrict__ adj_b, int ne) {
    int e = blockIdx.x * BLK + threadIdx.x;
    if (e < ne) {
        int s = src[e], d = dst[e];
        int p = atomicAdd(cur_f + d, 1);
        adj_f[p] = s;                      // fwd: node d aggregates from s
        int q = atomicAdd(cur_b + s, 1);
        adj_b[q] = d;                      // bwd: node s aggregates from d
    }
}

// ------------------------------------------------------------ GEMM ---------
// hs[r][c] = (sum_k x[r][k] * W[k][c]) * dinv[r]
__global__ __launch_bounds__(BLK) void k_gemm(const float* __restrict__ x,
                                              const float* __restrict__ Wf,
                                              const float* __restrict__ Wb,
                                              const float* __restrict__ dinv_f,
                                              const float* __restrict__ dinv_b,
                                              float* __restrict__ hs_f,
                                              float* __restrict__ hs_b, int n) {
    const int t = threadIdx.x;
    const int c = t & 127;
    const int half = t >> 7;
    const float* __restrict__ W    = half ? Wb : Wf;
    const float* __restrict__ dinv = half ? dinv_b : dinv_f;
    float* __restrict__ hs         = half ? hs_b : hs_f;

    float wcol[128];
#pragma unroll
    for (int k = 0; k < 128; ++k) wcol[k] = W[k * 128 + c];

    for (int r = blockIdx.x; r < n; r += gridDim.x) {
        const float* __restrict__ xr = x + (size_t)r * 128;
        float acc = 0.0f;
#pragma unroll
        for (int k = 0; k < 128; ++k) acc = fmaf(xr[k], wcol[k], acc);
        hs[(size_t)r * 128 + c] = acc * dinv[r];
    }
}

// ------------------------------------------------------------ gather -------
// one 128-thread group per node; thread owns one feature column.
// out[node][f] = relu( dinv_f[node]*(hs_f[node][f] + sum_{s in adj_f} hs_f[s][f])
//                    + dinv_b[node]*(hs_b[node][f] + sum_{d in adj_b} hs_b[d][f])
//                    + bf[f] + bb[f] )
__global__ __launch_bounds__(BLK) void k_gather(const int* __restrict__ off_f,
                                                const int* __restrict__ adj_f,
                                                const int* __restrict__ off_b,
                                                const int* __restrict__ adj_b,
                                                const float* __restrict__ hs_f,
                                                const float* __restrict__ hs_b,
                                                const float* __restrict__ dinv_f,
                                                const float* __restrict__ dinv_b,
                                                const float* __restrict__ bf,
                                                const float* __restrict__ bb,
                                                float* __restrict__ out, int n) {
    int node = blockIdx.x * 2 + (threadIdx.x >> 7);
    if (node >= n) return;
    int f = threadIdx.x & 127;

    float accf = hs_f[(size_t)node * 128 + f];     // self-loop term
    int jb = off_f[node], je = off_f[node + 1];
    for (int j = jb; j < je; ++j) {
        int nbr = adj_f[j];
        accf += hs_f[(size_t)nbr * 128 + f];
    }
    accf *= dinv_f[node];

    float accb = hs_b[(size_t)node * 128 + f];
    jb = off_b[node]; je = off_b[node + 1];
    for (int j = jb; j < je; ++j) {
        int nbr = adj_b[j];
        accb += hs_b[(size_t)nbr * 128 + f];
    }
    accb *= dinv_b[node];

    float v = accf + accb + bf[f] + bb[f];
    out[(size_t)node * 128 + f] = fmaxf(v, 0.0f);
}

// ------------------------------------------------------------ launcher -----
extern "C" void kernel_launch(void* const* d_in, const int* in_sizes, int n_in,
                              void* d_out, int out_size, void* d_ws, size_t ws_size,
                              hipStream_t stream) {
    const float* x  = (const float*)d_in[0];
    const int*   ei = (const int*)d_in[1];
    const float* Wf = (const float*)d_in[2];
    const float* bf = (const float*)d_in[3];
    const float* Wb = (const float*)d_in[4];
    const float* bb = (const float*)d_in[5];

    const int n  = in_sizes[0] / 128;   // 50000 nodes
    const int ne = in_sizes[1] / 2;     // 625000 edges
    const int* src = ei;
    const int* dst = ei + ne;
    float* out = (float*)d_out;

    // workspace layout (4-byte units)
    char* w = (char*)d_ws;
    float* dinv_f = (float*)w;                 w += (size_t)n * 4;
    float* dinv_b = (float*)w;                 w += (size_t)n * 4;
    float* hs_f   = (float*)w;                 w += (size_t)n * 128 * 4;
    float* hs_b   = (float*)w;                 w += (size_t)n * 128 * 4;
    int*   cnt_f  = (int*)w;                   w += (size_t)n * 4;
    int*   cnt_b  = (int*)w;                   w += (size_t)n * 4;
    int*   off_f  = (int*)w;                   w += (size_t)(n + 1) * 4;
    int*   off_b  = (int*)w;                   w += (size_t)(n + 1) * 4;
    int*   cur_f  = (int*)w;                   w += (size_t)n * 4;
    int*   cur_b  = (int*)w;                   w += (size_t)n * 4;
    int*   adj_f  = (int*)w;                   w += (size_t)ne * 4;
    int*   adj_b  = (int*)w;                   w += (size_t)ne * 4;
    int*   bsum_f = (int*)w;                   w += 256 * 4;
    int*   bsum_b = (int*)w;                   w += 256 * 4;

    const int gn  = (n + BLK - 1) / BLK;
    const int ge  = (ne + BLK - 1) / BLK;
    const int nb  = (n + 1023) / 1024;          // scan level-1 blocks (49)

    k_init  <<<gn, BLK, 0, stream>>>(cnt_f, cnt_b, n);
    k_count <<<ge, BLK, 0, stream>>>(src, dst, cnt_f, cnt_b, ne);
    k_rsqrt <<<gn, BLK, 0, stream>>>(cnt_f, cnt_b, dinv_f, dinv_b, n);

    k_scan1 <<<nb, BLK, 0, stream>>>(cnt_f, off_f, bsum_f, n);
    k_scan1 <<<nb, BLK, 0, stream>>>(cnt_b, off_b, bsum_b, n);
    k_scan2 <<<1,  BLK, 0, stream>>>(bsum_f, nb);
    k_scan2 <<<1,  BLK, 0, stream>>>(bsum_b, nb);
    k_scan3 <<<gn, BLK, 0, stream>>>(off_f, cur_f, bsum_f, n, ne);
    k_scan3 <<<gn, BLK, 0, stream>>>(off_b, cur_b, bsum_b, n, ne);

    k_fill  <<<ge, BLK, 0, stream>>>(src, dst, cur_f, cur_b, adj_f, adj_b, ne);

    k_gemm  <<<2048, BLK, 0, stream>>>(x, Wf, Wb, dinv_f, dinv_b, hs_f, hs_b, n);

    k_gather<<<(n + 1) / 2, BLK, 0, stream>>>(off_f, adj_f, off_b, adj_b,
                                              hs_f, hs_b, dinv_f, dinv_b,
                                              bf, bb, out, n);
}

// Round 3
// 351.115 us; speedup vs baseline: 2.2895x; 1.6690x over previous
//
#include <hip/hip_runtime.h>
#include <hip/hip_bf16.h>
#include <cstdint>

static constexpr int BLK = 256;

__device__ __forceinline__ float bf16lo(uint32_t u) { return __uint_as_float(u << 16); }
__device__ __forceinline__ float bf16hi(uint32_t u) { return __uint_as_float(u & 0xffff0000u); }

// ------------------------------------------------------------ init ---------
__global__ __launch_bounds__(BLK) void k_init(int* __restrict__ cnt_f,
                                              int* __restrict__ cnt_b, int n) {
    int i = blockIdx.x * BLK + threadIdx.x;
    if (i < n) { cnt_f[i] = 0; cnt_b[i] = 0; }
}

// --------------------------------------------- degree count + edge ranks ---
// rank trick: the atomic's return value IS the edge's slot within its bucket,
// so the CSR fill pass needs no atomics at all.
__global__ __launch_bounds__(BLK) void k_count(const int* __restrict__ src,
                                               const int* __restrict__ dst,
                                               int* __restrict__ cnt_f,
                                               int* __restrict__ cnt_b,
                                               int* __restrict__ rank_f,
                                               int* __restrict__ rank_b, int ne) {
    int e = blockIdx.x * BLK + threadIdx.x;
    if (e < ne) {
        rank_f[e] = atomicAdd(cnt_f + dst[e], 1);
        rank_b[e] = atomicAdd(cnt_b + src[e], 1);
    }
}

// ------------------------------------------------------------ rsqrt(deg) ---
__global__ __launch_bounds__(BLK) void k_rsqrt(const int* __restrict__ cnt_f,
                                               const int* __restrict__ cnt_b,
                                               float* __restrict__ dinv_f,
                                               float* __restrict__ dinv_b, int n) {
    int i = blockIdx.x * BLK + threadIdx.x;
    if (i < n) {
        dinv_f[i] = rsqrtf(1.0f + (float)cnt_f[i]);
        dinv_b[i] = rsqrtf(1.0f + (float)cnt_b[i]);
    }
}

// ------------------------------------------------------------ scan level 1 -
__global__ __launch_bounds__(BLK) void k_scan1(const int* __restrict__ in,
                                               int* __restrict__ out,
                                               int* __restrict__ bsum, int n) {
    __shared__ int lds[BLK];
    int base = blockIdx.x * 1024 + threadIdx.x * 4;
    int v0 = (base + 0 < n) ? in[base + 0] : 0;
    int v1 = (base + 1 < n) ? in[base + 1] : 0;
    int v2 = (base + 2 < n) ? in[base + 2] : 0;
    int v3 = (base + 3 < n) ? in[base + 3] : 0;
    int tsum = v0 + v1 + v2 + v3;
    lds[threadIdx.x] = tsum;
    __syncthreads();
    for (int off = 1; off < BLK; off <<= 1) {
        int t = (threadIdx.x >= off) ? lds[threadIdx.x - off] : 0;
        __syncthreads();
        lds[threadIdx.x] += t;
        __syncthreads();
    }
    int excl = lds[threadIdx.x] - tsum;
    if (base + 0 < n) out[base + 0] = excl;
    if (base + 1 < n) out[base + 1] = excl + v0;
    if (base + 2 < n) out[base + 2] = excl + v0 + v1;
    if (base + 3 < n) out[base + 3] = excl + v0 + v1 + v2;
    if (threadIdx.x == BLK - 1) bsum[blockIdx.x] = excl + tsum;
}

// ------------------------------------------------------------ scan level 2 -
__global__ __launch_bounds__(BLK) void k_scan2(int* __restrict__ bsum, int nb) {
    __shared__ int lds[BLK];
    int v = (threadIdx.x < nb) ? bsum[threadIdx.x] : 0;
    lds[threadIdx.x] = v;
    __syncthreads();
    for (int off = 1; off < BLK; off <<= 1) {
        int t = (threadIdx.x >= off) ? lds[threadIdx.x - off] : 0;
        __syncthreads();
        lds[threadIdx.x] += t;
        __syncthreads();
    }
    if (threadIdx.x < nb) bsum[threadIdx.x] = lds[threadIdx.x] - v;
}

// ------------------------------------------------------------ scan level 3 -
__global__ __launch_bounds__(BLK) void k_scan3(int* __restrict__ off,
                                               const int* __restrict__ bsum,
                                               int n, int ne) {
    int i = blockIdx.x * BLK + threadIdx.x;
    if (i < n) off[i] += bsum[i >> 10];
    if (i == 0) off[n] = ne;
}

// ------------------------------------------------------------ CSR fill -----
// atomic-free thanks to the rank trick.
__global__ __launch_bounds__(BLK) void k_fill(const int* __restrict__ src,
                                              const int* __restrict__ dst,
                                              const int* __restrict__ off_f,
                                              const int* __restrict__ off_b,
                                              const int* __restrict__ rank_f,
                                              const int* __restrict__ rank_b,
                                              int* __restrict__ adj_f,
                                              int* __restrict__ adj_b, int ne) {
    int e = blockIdx.x * BLK + threadIdx.x;
    if (e < ne) {
        int s = src[e], d = dst[e];
        adj_f[off_f[d] + rank_f[e]] = s;   // fwd: node d aggregates from s
        adj_b[off_b[s] + rank_b[e]] = d;   // bwd: node s aggregates from d
    }
}

// ------------------------------------------------------------ GEMM ---------
// hs[r][c] = bf16( (sum_k x[r][k] * W[k][c]) * dinv[r] )
__global__ __launch_bounds__(BLK) void k_gemm(const float* __restrict__ x,
                                              const float* __restrict__ Wf,
                                              const float* __restrict__ Wb,
                                              const float* __restrict__ dinv_f,
                                              const float* __restrict__ dinv_b,
                                              __hip_bfloat16* __restrict__ hs_f,
                                              __hip_bfloat16* __restrict__ hs_b, int n) {
    const int t = threadIdx.x;
    const int c = t & 127;
    const int half = t >> 7;
    const float* __restrict__ W    = half ? Wb : Wf;
    const float* __restrict__ dinv = half ? dinv_b : dinv_f;
    __hip_bfloat16* __restrict__ hs = half ? hs_b : hs_f;

    float wcol[128];
#pragma unroll
    for (int k = 0; k < 128; ++k) wcol[k] = W[k * 128 + c];

    for (int r = blockIdx.x; r < n; r += gridDim.x) {
        const float* __restrict__ xr = x + (size_t)r * 128;
        float acc = 0.0f;
#pragma unroll
        for (int k = 0; k < 128; ++k) acc = fmaf(xr[k], wcol[k], acc);
        hs[(size_t)r * 128 + c] = __float2bfloat16(acc * dinv[r]);
    }
}

// ------------------------------------------------------------ gather -------
// one 64-lane wave per node; lane owns features {2*lane, 2*lane+1} (bf16x2
// = one dword). Neighbor indices are loaded 64-at-a-time coalesced, then
// broadcast via __shfl; the hs fetches are 4x unrolled and independent.
__global__ __launch_bounds__(BLK) void k_gather(const int* __restrict__ off_f,
                                                const int* __restrict__ adj_f,
                                                const int* __restrict__ off_b,
                                                const int* __restrict__ adj_b,
                                                const uint32_t* __restrict__ hsf,
                                                const uint32_t* __restrict__ hsb,
                                                const float* __restrict__ dinv_f,
                                                const float* __restrict__ dinv_b,
                                                const float* __restrict__ bf,
                                                const float* __restrict__ bb,
                                                float* __restrict__ out, int n) {
    const int wave = threadIdx.x >> 6;
    const int lane = threadIdx.x & 63;
    const int node = blockIdx.x * 4 + wave;
    if (node >= n) return;

    float f0, f1, g0, g1;
    // ---- forward conv (group by dst, neighbors are srcs) ----
    {
        uint32_t u = hsf[(size_t)node * 64 + lane];          // self-loop
        f0 = bf16lo(u); f1 = bf16hi(u);
        int jb = off_f[node], je = off_f[node + 1];
        for (int b = jb; b < je; b += 64) {
            int m = min(64, je - b);
            int idx = (lane < m) ? adj_f[b + lane] : 0;
            int j = 0;
            for (; j + 4 <= m; j += 4) {
                int n0 = __shfl(idx, j + 0), n1 = __shfl(idx, j + 1);
                int n2 = __shfl(idx, j + 2), n3 = __shfl(idx, j + 3);
                uint32_t u0 = hsf[(size_t)n0 * 64 + lane];
                uint32_t u1 = hsf[(size_t)n1 * 64 + lane];
                uint32_t u2 = hsf[(size_t)n2 * 64 + lane];
                uint32_t u3 = hsf[(size_t)n3 * 64 + lane];
                f0 += bf16lo(u0) + bf16lo(u1) + bf16lo(u2) + bf16lo(u3);
                f1 += bf16hi(u0) + bf16hi(u1) + bf16hi(u2) + bf16hi(u3);
            }
            for (; j < m; ++j) {
                uint32_t uj = hsf[(size_t)__shfl(idx, j) * 64 + lane];
                f0 += bf16lo(uj); f1 += bf16hi(uj);
            }
        }
        float s = dinv_f[node];
        f0 *= s; f1 *= s;
    }
    // ---- backward conv (group by src, neighbors are dsts) ----
    {
        uint32_t u = hsb[(size_t)node * 64 + lane];
        g0 = bf16lo(u); g1 = bf16hi(u);
        int jb = off_b[node], je = off_b[node + 1];
        for (int b = jb; b < je; b += 64) {
            int m = min(64, je - b);
            int idx = (lane < m) ? adj_b[b + lane] : 0;
            int j = 0;
            for (; j + 4 <= m; j += 4) {
                int n0 = __shfl(idx, j + 0), n1 = __shfl(idx, j + 1);
                int n2 = __shfl(idx, j + 2), n3 = __shfl(idx, j + 3);
                uint32_t u0 = hsb[(size_t)n0 * 64 + lane];
                uint32_t u1 = hsb[(size_t)n1 * 64 + lane];
                uint32_t u2 = hsb[(size_t)n2 * 64 + lane];
                uint32_t u3 = hsb[(size_t)n3 * 64 + lane];
                g0 += bf16lo(u0) + bf16lo(u1) + bf16lo(u2) + bf16lo(u3);
                g1 += bf16hi(u0) + bf16hi(u1) + bf16hi(u2) + bf16hi(u3);
            }
            for (; j < m; ++j) {
                uint32_t uj = hsb[(size_t)__shfl(idx, j) * 64 + lane];
                g0 += bf16lo(uj); g1 += bf16hi(uj);
            }
        }
        float s = dinv_b[node];
        g0 *= s; g1 *= s;
    }

    const float2 biasf = ((const float2*)bf)[lane];
    const float2 biasb = ((const float2*)bb)[lane];
    float v0 = f0 + g0 + biasf.x + biasb.x;
    float v1 = f1 + g1 + biasf.y + biasb.y;
    ((float2*)out)[(size_t)node * 64 + lane] =
        make_float2(fmaxf(v0, 0.0f), fmaxf(v1, 0.0f));
}

// ------------------------------------------------------------ launcher -----
extern "C" void kernel_launch(void* const* d_in, const int* in_sizes, int n_in,
                              void* d_out, int out_size, void* d_ws, size_t ws_size,
                              hipStream_t stream) {
    const float* x  = (const float*)d_in[0];
    const int*   ei = (const int*)d_in[1];
    const float* Wf = (const float*)d_in[2];
    const float* bf = (const float*)d_in[3];
    const float* Wb = (const float*)d_in[4];
    const float* bb = (const float*)d_in[5];

    const int n  = in_sizes[0] / 128;   // 50000 nodes
    const int ne = in_sizes[1] / 2;     // 625000 edges
    const int* src = ei;
    const int* dst = ei + ne;
    float* out = (float*)d_out;

    // workspace layout
    char* w = (char*)d_ws;
    float* dinv_f = (float*)w;                    w += (size_t)n * 4;
    float* dinv_b = (float*)w;                    w += (size_t)n * 4;
    __hip_bfloat16* hs_f = (__hip_bfloat16*)w;    w += (size_t)n * 128 * 2;
    __hip_bfloat16* hs_b = (__hip_bfloat16*)w;    w += (size_t)n * 128 * 2;
    int*   cnt_f  = (int*)w;                      w += (size_t)n * 4;
    int*   cnt_b  = (int*)w;                      w += (size_t)n * 4;
    int*   off_f  = (int*)w;                      w += (size_t)(n + 1) * 4;
    int*   off_b  = (int*)w;                      w += (size_t)(n + 1) * 4;
    int*   rank_f = (int*)w;                      w += (size_t)ne * 4;
    int*   rank_b = (int*)w;                      w += (size_t)ne * 4;
    int*   adj_f  = (int*)w;                      w += (size_t)ne * 4;
    int*   adj_b  = (int*)w;                      w += (size_t)ne * 4;
    int*   bsum_f = (int*)w;                      w += 256 * 4;
    int*   bsum_b = (int*)w;                      w += 256 * 4;

    const int gn = (n + BLK - 1) / BLK;
    const int ge = (ne + BLK - 1) / BLK;
    const int nb = (n + 1023) / 1024;

    k_init  <<<gn, BLK, 0, stream>>>(cnt_f, cnt_b, n);
    k_count <<<ge, BLK, 0, stream>>>(src, dst, cnt_f, cnt_b, rank_f, rank_b, ne);
    k_rsqrt <<<gn, BLK, 0, stream>>>(cnt_f, cnt_b, dinv_f, dinv_b, n);

    k_scan1 <<<nb, BLK, 0, stream>>>(cnt_f, off_f, bsum_f, n);
    k_scan1 <<<nb, BLK, 0, stream>>>(cnt_b, off_b, bsum_b, n);
    k_scan2 <<<1,  BLK, 0, stream>>>(bsum_f, nb);
    k_scan2 <<<1,  BLK, 0, stream>>>(bsum_b, nb);
    k_scan3 <<<gn, BLK, 0, stream>>>(off_f, bsum_f, n, ne);
    k_scan3 <<<gn, BLK, 0, stream>>>(off_b, bsum_b, n, ne);

    k_fill  <<<ge, BLK, 0, stream>>>(src, dst, off_f, off_b, rank_f, rank_b,
                                     adj_f, adj_b, ne);

    k_gemm  <<<2048, BLK, 0, stream>>>(x, Wf, Wb, dinv_f, dinv_b, hs_f, hs_b, n);

    k_gather<<<(n + 3) / 4, BLK, 0, stream>>>(off_f, adj_f, off_b, adj_b,
                                              (const uint32_t*)hs_f,
                                              (const uint32_t*)hs_b,
                                              dinv_f, dinv_b, bf, bb, out, n);
}

// Round 4
// 278.400 us; speedup vs baseline: 2.8875x; 1.2612x over previous
//
#include <hip/hip_runtime.h>
#include <hip/hip_bf16.h>
#include <cstdint>

static constexpr int BLK = 256;

typedef __attribute__((ext_vector_type(8))) short bf16x8;   // 8 bf16 = 4 VGPRs
typedef __attribute__((ext_vector_type(4))) float f32x4;

__device__ __forceinline__ float bf16lo(uint32_t u) { return __uint_as_float(u << 16); }
__device__ __forceinline__ float bf16hi(uint32_t u) { return __uint_as_float(u & 0xffff0000u); }
__device__ __forceinline__ unsigned short f2bf(float f) {
    __hip_bfloat16 h = __float2bfloat16(f);
    return *(unsigned short*)&h;
}

// ------------------------------------------------------------ init ---------
__global__ __launch_bounds__(BLK) void k_init(int* __restrict__ cnt_f,
                                              int* __restrict__ cnt_b, int n) {
    int i = blockIdx.x * BLK + threadIdx.x;
    if (i < n) { cnt_f[i] = 0; cnt_b[i] = 0; }
}

// --------------------------------------------- degree count + edge ranks ---
__global__ __launch_bounds__(BLK) void k_count(const int* __restrict__ src,
                                               const int* __restrict__ dst,
                                               int* __restrict__ cnt_f,
                                               int* __restrict__ cnt_b,
                                               int* __restrict__ rank_f,
                                               int* __restrict__ rank_b, int ne) {
    int e = blockIdx.x * BLK + threadIdx.x;
    if (e < ne) {
        rank_f[e] = atomicAdd(cnt_f + dst[e], 1);
        rank_b[e] = atomicAdd(cnt_b + src[e], 1);
    }
}

// ------------------------------------------------------------ rsqrt(deg) ---
__global__ __launch_bounds__(BLK) void k_rsqrt(const int* __restrict__ cnt_f,
                                               const int* __restrict__ cnt_b,
                                               float* __restrict__ dinv_f,
                                               float* __restrict__ dinv_b, int n) {
    int i = blockIdx.x * BLK + threadIdx.x;
    if (i < n) {
        dinv_f[i] = rsqrtf(1.0f + (float)cnt_f[i]);
        dinv_b[i] = rsqrtf(1.0f + (float)cnt_b[i]);
    }
}

// ------------------------------------------------------------ scan level 1 -
__global__ __launch_bounds__(BLK) void k_scan1(const int* __restrict__ in,
                                               int* __restrict__ out,
                                               int* __restrict__ bsum, int n) {
    __shared__ int lds[BLK];
    int base = blockIdx.x * 1024 + threadIdx.x * 4;
    int v0 = (base + 0 < n) ? in[base + 0] : 0;
    int v1 = (base + 1 < n) ? in[base + 1] : 0;
    int v2 = (base + 2 < n) ? in[base + 2] : 0;
    int v3 = (base + 3 < n) ? in[base + 3] : 0;
    int tsum = v0 + v1 + v2 + v3;
    lds[threadIdx.x] = tsum;
    __syncthreads();
    for (int off = 1; off < BLK; off <<= 1) {
        int t = (threadIdx.x >= off) ? lds[threadIdx.x - off] : 0;
        __syncthreads();
        lds[threadIdx.x] += t;
        __syncthreads();
    }
    int excl = lds[threadIdx.x] - tsum;
    if (base + 0 < n) out[base + 0] = excl;
    if (base + 1 < n) out[base + 1] = excl + v0;
    if (base + 2 < n) out[base + 2] = excl + v0 + v1;
    if (base + 3 < n) out[base + 3] = excl + v0 + v1 + v2;
    if (threadIdx.x == BLK - 1) bsum[blockIdx.x] = excl + tsum;
}

// ------------------------------------------------------------ scan level 2 -
__global__ __launch_bounds__(BLK) void k_scan2(int* __restrict__ bsum, int nb) {
    __shared__ int lds[BLK];
    int v = (threadIdx.x < nb) ? bsum[threadIdx.x] : 0;
    lds[threadIdx.x] = v;
    __syncthreads();
    for (int off = 1; off < BLK; off <<= 1) {
        int t = (threadIdx.x >= off) ? lds[threadIdx.x - off] : 0;
        __syncthreads();
        lds[threadIdx.x] += t;
        __syncthreads();
    }
    if (threadIdx.x < nb) bsum[threadIdx.x] = lds[threadIdx.x] - v;
}

// ------------------------------------------------------------ scan level 3 -
__global__ __launch_bounds__(BLK) void k_scan3(int* __restrict__ off,
                                               const int* __restrict__ bsum,
                                               int n, int ne) {
    int i = blockIdx.x * BLK + threadIdx.x;
    if (i < n) off[i] += bsum[i >> 10];
    if (i == 0) off[n] = ne;
}

// ------------------------------------------------------------ CSR fill -----
__global__ __launch_bounds__(BLK) void k_fill(const int* __restrict__ src,
                                              const int* __restrict__ dst,
                                              const int* __restrict__ off_f,
                                              const int* __restrict__ off_b,
                                              const int* __restrict__ rank_f,
                                              const int* __restrict__ rank_b,
                                              int* __restrict__ adj_f,
                                              int* __restrict__ adj_b, int ne) {
    int e = blockIdx.x * BLK + threadIdx.x;
    if (e < ne) {
        int s = src[e], d = dst[e];
        adj_f[off_f[d] + rank_f[e]] = s;
        adj_b[off_b[s] + rank_b[e]] = d;
    }
}

// ------------------------------------------------------- x -> bf16 --------
__global__ __launch_bounds__(BLK) void k_cvt_x(const float4* __restrict__ x4,
                                               ushort4* __restrict__ xb4, int total4) {
    int i = blockIdx.x * BLK + threadIdx.x;
    if (i < total4) {
        float4 v = x4[i];
        ushort4 o;
        o.x = f2bf(v.x); o.y = f2bf(v.y); o.z = f2bf(v.z); o.w = f2bf(v.w);
        xb4[i] = o;
    }
}

// --------------------------------------- W -> bf16 + transpose to [n][k] ---
// WT[c][k] = W[k][c]; writes coalesced (c=idx>>7, k=idx&127), reads L2-cached.
__global__ __launch_bounds__(BLK) void k_cvt_w(const float* __restrict__ Wf,
                                               const float* __restrict__ Wb,
                                               unsigned short* __restrict__ WTf,
                                               unsigned short* __restrict__ WTb) {
    for (int idx = threadIdx.x; idx < 128 * 128; idx += BLK) {
        int c = idx >> 7, k = idx & 127;
        WTf[c * 128 + k] = f2bf(Wf[k * 128 + c]);
        WTb[c * 128 + k] = f2bf(Wb[k * 128 + c]);
    }
}

// ------------------------------------------------------------ MFMA GEMM ----
// block = 16 M-rows; wave w: conv = w>>1, n-half = (w&1)*64.
// A[m=lane&15][k=quad*8+j] from xb row-major; B[k][n] with n=lane&15,
// k=quad*8+j from WT[n][k] row-major -> both single 16B loads.
// C/D: col=lane&15, row=quad*4+reg.
__global__ __launch_bounds__(BLK) void k_gemm_mfma(
        const unsigned short* __restrict__ xb,    // [n][128] bf16
        const unsigned short* __restrict__ WTf,   // [128][128] bf16, [n][k]
        const unsigned short* __restrict__ WTb,
        const float* __restrict__ dinv_f,
        const float* __restrict__ dinv_b,
        unsigned short* __restrict__ hs_f,        // [n][128] bf16
        unsigned short* __restrict__ hs_b, int n) {
    const int wave = threadIdx.x >> 6;
    const int lane = threadIdx.x & 63;
    const int conv = wave >> 1;
    const int n0   = (wave & 1) * 64;
    const int m0   = blockIdx.x * 16;
    const int q    = lane >> 4;
    const int t16  = lane & 15;

    const unsigned short* __restrict__ WT = conv ? WTb : WTf;
    const float* __restrict__ dinv        = conv ? dinv_b : dinv_f;
    unsigned short* __restrict__ hs       = conv ? hs_b : hs_f;

    // A fragments for 4 K-steps (row clamped for safety; n % 16 == 0 here)
    int arow = m0 + t16; if (arow >= n) arow = n - 1;
    bf16x8 a[4];
#pragma unroll
    for (int s = 0; s < 4; ++s)
        a[s] = *(const bf16x8*)(xb + (size_t)arow * 128 + s * 32 + q * 8);

    const float4 dv = *(const float4*)(dinv + m0 + q * 4);

#pragma unroll
    for (int t = 0; t < 4; ++t) {
        const unsigned short* wrow = WT + (size_t)(n0 + t * 16 + t16) * 128;
        f32x4 c = {0.f, 0.f, 0.f, 0.f};
#pragma unroll
        for (int s = 0; s < 4; ++s) {
            bf16x8 b = *(const bf16x8*)(wrow + s * 32 + q * 8);
            c = __builtin_amdgcn_mfma_f32_16x16x32_bf16(a[s], b, c, 0, 0, 0);
        }
#pragma unroll
        for (int r = 0; r < 4; ++r) {
            int row = m0 + q * 4 + r;
            if (row < n) {
                float vr = (r == 0 ? dv.x : r == 1 ? dv.y : r == 2 ? dv.z : dv.w);
                hs[(size_t)row * 128 + n0 + t * 16 + t16] = f2bf(c[r] * vr);
            }
        }
    }
}

// ------------------------------------------------------------ gather -------
__global__ __launch_bounds__(BLK) void k_gather(const int* __restrict__ off_f,
                                                const int* __restrict__ adj_f,
                                                const int* __restrict__ off_b,
                                                const int* __restrict__ adj_b,
                                                const uint32_t* __restrict__ hsf,
                                                const uint32_t* __restrict__ hsb,
                                                const float* __restrict__ dinv_f,
                                                const float* __restrict__ dinv_b,
                                                const float* __restrict__ bf,
                                                const float* __restrict__ bb,
                                                float* __restrict__ out, int n) {
    const int wave = threadIdx.x >> 6;
    const int lane = threadIdx.x & 63;
    const int node = blockIdx.x * 4 + wave;
    if (node >= n) return;

    float f0, f1, g0, g1;
    {
        uint32_t u = hsf[(size_t)node * 64 + lane];
        f0 = bf16lo(u); f1 = bf16hi(u);
        int jb = off_f[node], je = off_f[node + 1];
        for (int b = jb; b < je; b += 64) {
            int m = min(64, je - b);
            int idx = (lane < m) ? adj_f[b + lane] : 0;
            int j = 0;
            for (; j + 4 <= m; j += 4) {
                int n0 = __shfl(idx, j + 0), n1 = __shfl(idx, j + 1);
                int n2 = __shfl(idx, j + 2), n3 = __shfl(idx, j + 3);
                uint32_t u0 = hsf[(size_t)n0 * 64 + lane];
                uint32_t u1 = hsf[(size_t)n1 * 64 + lane];
                uint32_t u2 = hsf[(size_t)n2 * 64 + lane];
                uint32_t u3 = hsf[(size_t)n3 * 64 + lane];
                f0 += bf16lo(u0) + bf16lo(u1) + bf16lo(u2) + bf16lo(u3);
                f1 += bf16hi(u0) + bf16hi(u1) + bf16hi(u2) + bf16hi(u3);
            }
            for (; j < m; ++j) {
                uint32_t uj = hsf[(size_t)__shfl(idx, j) * 64 + lane];
                f0 += bf16lo(uj); f1 += bf16hi(uj);
            }
        }
        float s = dinv_f[node];
        f0 *= s; f1 *= s;
    }
    {
        uint32_t u = hsb[(size_t)node * 64 + lane];
        g0 = bf16lo(u); g1 = bf16hi(u);
        int jb = off_b[node], je = off_b[node + 1];
        for (int b = jb; b < je; b += 64) {
            int m = min(64, je - b);
            int idx = (lane < m) ? adj_b[b + lane] : 0;
            int j = 0;
            for (; j + 4 <= m; j += 4) {
                int n0 = __shfl(idx, j + 0), n1 = __shfl(idx, j + 1);
                int n2 = __shfl(idx, j + 2), n3 = __shfl(idx, j + 3);
                uint32_t u0 = hsb[(size_t)n0 * 64 + lane];
                uint32_t u1 = hsb[(size_t)n1 * 64 + lane];
                uint32_t u2 = hsb[(size_t)n2 * 64 + lane];
                uint32_t u3 = hsb[(size_t)n3 * 64 + lane];
                g0 += bf16lo(u0) + bf16lo(u1) + bf16lo(u2) + bf16lo(u3);
                g1 += bf16hi(u0) + bf16hi(u1) + bf16hi(u2) + bf16hi(u3);
            }
            for (; j < m; ++j) {
                uint32_t uj = hsb[(size_t)__shfl(idx, j) * 64 + lane];
                g0 += bf16lo(uj); g1 += bf16hi(uj);
            }
        }
        float s = dinv_b[node];
        g0 *= s; g1 *= s;
    }

    const float2 biasf = ((const float2*)bf)[lane];
    const float2 biasb = ((const float2*)bb)[lane];
    float v0 = f0 + g0 + biasf.x + biasb.x;
    float v1 = f1 + g1 + biasf.y + biasb.y;
    ((float2*)out)[(size_t)node * 64 + lane] =
        make_float2(fmaxf(v0, 0.0f), fmaxf(v1, 0.0f));
}

// ------------------------------------------------------------ launcher -----
extern "C" void kernel_launch(void* const* d_in, const int* in_sizes, int n_in,
                              void* d_out, int out_size, void* d_ws, size_t ws_size,
                              hipStream_t stream) {
    const float* x  = (const float*)d_in[0];
    const int*   ei = (const int*)d_in[1];
    const float* Wf = (const float*)d_in[2];
    const float* bf = (const float*)d_in[3];
    const float* Wb = (const float*)d_in[4];
    const float* bb = (const float*)d_in[5];

    const int n  = in_sizes[0] / 128;   // 50000
    const int ne = in_sizes[1] / 2;     // 625000
    const int* src = ei;
    const int* dst = ei + ne;
    float* out = (float*)d_out;

    // workspace layout (16B-aligned chunks)
    char* w = (char*)d_ws;
    float* dinv_f = (float*)w;                      w += (size_t)n * 4;      // n*4 % 16 == 0
    float* dinv_b = (float*)w;                      w += (size_t)n * 4;
    unsigned short* hs_f = (unsigned short*)w;      w += (size_t)n * 128 * 2;
    unsigned short* hs_b = (unsigned short*)w;      w += (size_t)n * 128 * 2;
    unsigned short* xb   = (unsigned short*)w;      w += (size_t)n * 128 * 2;
    unsigned short* WTf  = (unsigned short*)w;      w += 128 * 128 * 2;
    unsigned short* WTb  = (unsigned short*)w;      w += 128 * 128 * 2;
    int*   cnt_f  = (int*)w;                        w += (size_t)n * 4;
    int*   cnt_b  = (int*)w;                        w += (size_t)n * 4;
    int*   off_f  = (int*)w;                        w += (size_t)(n + 4) * 4;
    int*   off_b  = (int*)w;                        w += (size_t)(n + 4) * 4;
    int*   rank_f = (int*)w;                        w += (size_t)ne * 4;
    int*   rank_b = (int*)w;                        w += (size_t)ne * 4;
    int*   adj_f  = (int*)w;                        w += (size_t)ne * 4;
    int*   adj_b  = (int*)w;                        w += (size_t)ne * 4;
    int*   bsum_f = (int*)w;                        w += 256 * 4;
    int*   bsum_b = (int*)w;                        w += 256 * 4;

    const int gn = (n + BLK - 1) / BLK;
    const int ge = (ne + BLK - 1) / BLK;
    const int nb = (n + 1023) / 1024;
    const int total4 = n * 32;          // float4 groups in x

    k_init  <<<gn, BLK, 0, stream>>>(cnt_f, cnt_b, n);
    k_count <<<ge, BLK, 0, stream>>>(src, dst, cnt_f, cnt_b, rank_f, rank_b, ne);
    k_rsqrt <<<gn, BLK, 0, stream>>>(cnt_f, cnt_b, dinv_f, dinv_b, n);

    k_scan1 <<<nb, BLK, 0, stream>>>(cnt_f, off_f, bsum_f, n);
    k_scan1 <<<nb, BLK, 0, stream>>>(cnt_b, off_b, bsum_b, n);
    k_scan2 <<<1,  BLK, 0, stream>>>(bsum_f, nb);
    k_scan2 <<<1,  BLK, 0, stream>>>(bsum_b, nb);
    k_scan3 <<<gn, BLK, 0, stream>>>(off_f, bsum_f, n, ne);
    k_scan3 <<<gn, BLK, 0, stream>>>(off_b, bsum_b, n, ne);

    k_fill  <<<ge, BLK, 0, stream>>>(src, dst, off_f, off_b, rank_f, rank_b,
                                     adj_f, adj_b, ne);

    k_cvt_x <<<(total4 + BLK - 1) / BLK, BLK, 0, stream>>>((const float4*)x,
                                                           (ushort4*)xb, total4);
    k_cvt_w <<<1, BLK, 0, stream>>>(Wf, Wb, WTf, WTb);

    k_gemm_mfma<<<(n + 15) / 16, BLK, 0, stream>>>(xb, WTf, WTb, dinv_f, dinv_b,
                                                   hs_f, hs_b, n);

    k_gather<<<(n + 3) / 4, BLK, 0, stream>>>(off_f, adj_f, off_b, adj_b,
                                              (const uint32_t*)hs_f,
                                              (const uint32_t*)hs_b,
                                              dinv_f, dinv_b, bf, bb, out, n);
}